// Round 1
// baseline (746.697 us; speedup 1.0000x reference)
//
#include <hip/hip_runtime.h>
#include <cstdint>
#include <cstddef>

// ---------------------------------------------------------------------------
// MultiHeadCrossAttention, W8A8-style fake-quant, MI355X (gfx950)
// B=2, N=4096, M=512, C=2048, H=16, Dh=128
// Pipeline: qdq(x)->bf16 ; GEMM1 q ; GEMM2 kv ; transpose V ; fused attention ;
//           qdq(o)->bf16 ; GEMM3 out(fp32)
// All GEMMs: bf16 MFMA 16x16x32, fp32 accumulate, fragment-order LDS staged
// via global_load_lds (16B). qdq math done exactly in fp32 (RNE).
// ---------------------------------------------------------------------------

typedef __bf16 bf16_t;
typedef __bf16 bf16x8 __attribute__((ext_vector_type(8)));
typedef __bf16 bf16x4v __attribute__((ext_vector_type(4)));
typedef float f32x4 __attribute__((ext_vector_type(4)));

// async global->LDS, 16B per lane; lds must be wave-uniform chunk base
__device__ __forceinline__ void gld16(void* lds, const void* g) {
    __builtin_amdgcn_global_load_lds(
        (__attribute__((address_space(1))) uint32_t*)(uintptr_t)g,
        (__attribute__((address_space(3))) uint32_t*)(uint32_t)(uintptr_t)lds,
        16, 0, 0);
}

// ---------------------------------------------------------------------------
// Per-row symmetric int8 fake-quant (exact fp32 math), output bf16.
// s = max(amax/127, 1e-8); out = clip(rint(x/s), -127, 127) * s
// ---------------------------------------------------------------------------
template <typename T>
__global__ __launch_bounds__(256) void quant_rows(const T* __restrict__ in,
                                                  bf16_t* __restrict__ out,
                                                  int K) {
    const int tid = threadIdx.x;
    const size_t row = blockIdx.x;
    const T* rp = in + row * (size_t)K;
    float m = 0.f;
    for (int c = tid; c < K; c += 256) m = fmaxf(m, fabsf((float)rp[c]));
    __shared__ float red[256];
    red[tid] = m;
    __syncthreads();
    for (int s = 128; s > 0; s >>= 1) {
        if (tid < s) red[tid] = fmaxf(red[tid], red[tid + s]);
        __syncthreads();
    }
    const float scale = fmaxf(red[0] * (1.0f / 127.0f), 1e-8f);
    bf16_t* op = out + row * (size_t)K;
    for (int c = tid; c < K; c += 256) {
        float v = (float)rp[c];
        float q = rintf(v / scale);               // RNE, matches jnp.round
        q = fminf(127.f, fmaxf(-127.f, q));
        op[c] = (bf16_t)(q * scale);
    }
}

// fp32 -> bf16 convert (vectorized x4)
__global__ __launch_bounds__(256) void cvt_bf16(const float4* __restrict__ in,
                                                bf16x4v* __restrict__ out,
                                                int n4) {
    int i = blockIdx.x * 256 + threadIdx.x;
    if (i < n4) {
        float4 v = in[i];
        bf16x4v o;
        o[0] = (bf16_t)v.x; o[1] = (bf16_t)v.y; o[2] = (bf16_t)v.z; o[3] = (bf16_t)v.w;
        out[i] = o;
    }
}

// ---------------------------------------------------------------------------
// GEMM: C[M x N] = A[M x K] * Bt[N x K]^T + bias[N]
// 128x128 tile, BK=32, 256 threads (4 waves in 2x2), mfma 16x16x32 bf16.
// LDS tiles in fragment order: chunk c (=16-row subtile), lane l holds
// rows c*16+(l&15), cols k0 + (l>>4)*8 .. +8  -> one contiguous 16B.
// ---------------------------------------------------------------------------
template <int OUT_F32>
__global__ __launch_bounds__(256) void gemm_bt(const bf16_t* __restrict__ A,
                                               const bf16_t* __restrict__ Bt,
                                               const float* __restrict__ bias,
                                               void* __restrict__ Cout,
                                               int M, int N, int K) {
    __shared__ __align__(16) bf16_t sA[4096];  // 8 chunks x 64 lanes x 8 bf16
    __shared__ __align__(16) bf16_t sB[4096];

    const int tid = threadIdx.x;
    const int l = tid & 63, w = tid >> 6;
    const int lm = l & 15, quad = l >> 4;
    const int wm = w & 1, wn = w >> 1;
    const size_t bm = (size_t)blockIdx.y * 128;
    const size_t bn = (size_t)blockIdx.x * 128;

    f32x4 acc[4][4] = {};
    const int nk = K >> 5;
    for (int kt = 0; kt < nk; ++kt) {
        const int k0 = kt << 5;
        __syncthreads();  // previous tile's reads done
#pragma unroll
        for (int it = 0; it < 2; ++it) {
            const int c = w + it * 4;                        // 0..7, wave-uniform
            const int row = c * 16 + lm;
            gld16(sA + c * 512, A + (bm + row) * (size_t)K + k0 + quad * 8);
            gld16(sB + c * 512, Bt + (bn + row) * (size_t)K + k0 + quad * 8);
        }
        __syncthreads();  // drains vmcnt(0): staged data visible
        bf16x8 af[4], bfr[4];
#pragma unroll
        for (int i = 0; i < 4; ++i)
            af[i] = *(const bf16x8*)(sA + (wm * 4 + i) * 512 + l * 8);
#pragma unroll
        for (int j = 0; j < 4; ++j)
            bfr[j] = *(const bf16x8*)(sB + (wn * 4 + j) * 512 + l * 8);
#pragma unroll
        for (int i = 0; i < 4; ++i)
#pragma unroll
            for (int j = 0; j < 4; ++j)
                acc[i][j] = __builtin_amdgcn_mfma_f32_16x16x32_bf16(af[i], bfr[j], acc[i][j], 0, 0, 0);
    }
    // epilogue: D row = quad*4+reg, col = lane&15  (verified C/D layout)
#pragma unroll
    for (int i = 0; i < 4; ++i) {
#pragma unroll
        for (int j = 0; j < 4; ++j) {
            const size_t col = bn + wn * 64 + j * 16 + lm;
            const float bv = bias[col];
#pragma unroll
            for (int r = 0; r < 4; ++r) {
                const size_t row = bm + wm * 64 + i * 16 + quad * 4 + r;
                const float v = acc[i][j][r] + bv;
                if (OUT_F32)
                    ((float*)Cout)[row * (size_t)N + col] = v;
                else
                    ((bf16_t*)Cout)[row * (size_t)N + col] = (bf16_t)v;
            }
        }
    }
}

// ---------------------------------------------------------------------------
// Transpose V half of kv into vT[(b*2048 + c') * 512 + m], c' = h*128+d.
// ---------------------------------------------------------------------------
__global__ __launch_bounds__(256) void transpose_v(const bf16_t* __restrict__ kvb,
                                                   bf16_t* __restrict__ vT) {
    __shared__ bf16_t t[32][34];  // +2 pad to dodge bank conflicts
    const int b = blockIdx.z;
    const int m0 = blockIdx.y * 32;
    const int c0 = blockIdx.x * 32;
    const int tid = threadIdx.x;
    const int r = tid >> 5, c = tid & 31;
#pragma unroll
    for (int it = 0; it < 4; ++it) {
        const int rr = r + it * 8;
        t[rr][c] = kvb[(size_t)(b * 512 + m0 + rr) * 4096 + 2048 + c0 + c];
    }
    __syncthreads();
#pragma unroll
    for (int it = 0; it < 4; ++it) {
        const int rr = r + it * 8;  // vT row within tile (c' index)
        vT[(size_t)(b * 2048 + c0 + rr) * 512 + m0 + c] = t[c][rr];
    }
}

// ---------------------------------------------------------------------------
// Fused attention: per (b, h, 32 q-rows). Register-resident S (32x512 / wave
// cols), shuffle+LDS softmax, P -> LDS in A-fragment order, PV via MFMA with
// V staged from vT (B-fragment contiguous). LDS total ~57KB.
// ---------------------------------------------------------------------------
__global__ __launch_bounds__(256) void attn_kernel(const bf16_t* __restrict__ qbf,
                                                   const bf16_t* __restrict__ kvbf,
                                                   const bf16_t* __restrict__ vT,
                                                   bf16_t* __restrict__ obf) {
    constexpr float SCALE = 0.08838834764831845f;  // 1/sqrt(128)
    __shared__ __align__(16) bf16_t sQ[4096];    // 8KB : 8 chunks (mt*4+kt)
    __shared__ __align__(16) bf16_t sKV[8192];   // 16KB: K tiles then V tiles
    __shared__ __align__(16) bf16_t sP[16384];   // 32KB: 32 chunks (mt*16+ktg)
    __shared__ float redM[4][32];
    __shared__ float redS[4][32];

    const int tid = threadIdx.x;
    const int l = tid & 63, w = tid >> 6;
    const int lm = l & 15, quad = l >> 4;
    const int b = blockIdx.z, h = blockIdx.y;
    const int n0 = blockIdx.x * 32;

    // ---- stage Q tile [32 x 128] in A-fragment order ----
#pragma unroll
    for (int it = 0; it < 2; ++it) {
        const int c = w + it * 4;  // mt = c>>2, kt = c&3
        const int mt = c >> 2, kt = c & 3;
        gld16(sQ + c * 512,
              qbf + (size_t)(b * 4096 + n0 + mt * 16 + lm) * 2048 + h * 128 + kt * 32 + quad * 8);
    }

    // ---- S = Q K^T : 8 tiles of 64 attention-cols ----
    f32x4 sfr[8][2] = {};
#pragma unroll
    for (int t8 = 0; t8 < 8; ++t8) {
        __syncthreads();
#pragma unroll
        for (int it = 0; it < 4; ++it) {
            const int c = w + it * 4;  // nt = c>>2, ktc = c&3
            const int nt = c >> 2, ktc = c & 3;
            gld16(sKV + c * 512,
                  kvbf + (size_t)(b * 512 + t8 * 64 + nt * 16 + lm) * 4096 + h * 128 + ktc * 32 + quad * 8);
        }
        __syncthreads();
#pragma unroll
        for (int kt = 0; kt < 4; ++kt) {
            bf16x8 a0 = *(const bf16x8*)(sQ + kt * 512 + l * 8);
            bf16x8 a1 = *(const bf16x8*)(sQ + (4 + kt) * 512 + l * 8);
            bf16x8 bb = *(const bf16x8*)(sKV + (w * 4 + kt) * 512 + l * 8);
            sfr[t8][0] = __builtin_amdgcn_mfma_f32_16x16x32_bf16(a0, bb, sfr[t8][0], 0, 0, 0);
            sfr[t8][1] = __builtin_amdgcn_mfma_f32_16x16x32_bf16(a1, bb, sfr[t8][1], 0, 0, 0);
        }
    }

    // ---- softmax (lane holds rows mt*16+quad*4+r, cols t8*64 + w*16 + lm) ----
    float mymax[2][4], inv[2][4];
#pragma unroll
    for (int mt = 0; mt < 2; ++mt)
#pragma unroll
        for (int r = 0; r < 4; ++r) {
            float m = -3.0e38f;
#pragma unroll
            for (int t8 = 0; t8 < 8; ++t8) m = fmaxf(m, sfr[t8][mt][r]);
            m = fmaxf(m, __shfl_xor(m, 1));
            m = fmaxf(m, __shfl_xor(m, 2));
            m = fmaxf(m, __shfl_xor(m, 4));
            m = fmaxf(m, __shfl_xor(m, 8));
            mymax[mt][r] = m;
        }
    if (lm == 0) {
#pragma unroll
        for (int mt = 0; mt < 2; ++mt)
#pragma unroll
            for (int r = 0; r < 4; ++r)
                redM[w][mt * 16 + quad * 4 + r] = mymax[mt][r];
    }
    __syncthreads();
    float mysum[2][4];
#pragma unroll
    for (int mt = 0; mt < 2; ++mt)
#pragma unroll
        for (int r = 0; r < 4; ++r) {
            const int row = mt * 16 + quad * 4 + r;
            const float M =
                fmaxf(fmaxf(redM[0][row], redM[1][row]), fmaxf(redM[2][row], redM[3][row])) * SCALE;
            float s = 0.f;
#pragma unroll
            for (int t8 = 0; t8 < 8; ++t8) {
                const float p = __expf(sfr[t8][mt][r] * SCALE - M);
                sfr[t8][mt][r] = p;
                s += p;
            }
            s += __shfl_xor(s, 1);
            s += __shfl_xor(s, 2);
            s += __shfl_xor(s, 4);
            s += __shfl_xor(s, 8);
            mysum[mt][r] = s;
        }
    if (lm == 0) {
#pragma unroll
        for (int mt = 0; mt < 2; ++mt)
#pragma unroll
            for (int r = 0; r < 4; ++r)
                redS[w][mt * 16 + quad * 4 + r] = mysum[mt][r];
    }
    __syncthreads();
#pragma unroll
    for (int mt = 0; mt < 2; ++mt)
#pragma unroll
        for (int r = 0; r < 4; ++r) {
            const int row = mt * 16 + quad * 4 + r;
            inv[mt][r] = 1.f / (redS[0][row] + redS[1][row] + redS[2][row] + redS[3][row]);
        }
    // ---- write unnormalized P into sP (PV A-fragment order) ----
    {
        const int q2 = (w & 1) * 2 + (lm >> 3);
        const int j = lm & 7;
#pragma unroll
        for (int t8 = 0; t8 < 8; ++t8) {
            const int ktg = t8 * 2 + (w >> 1);
#pragma unroll
            for (int mt = 0; mt < 2; ++mt)
#pragma unroll
                for (int r = 0; r < 4; ++r)
                    sP[(mt * 16 + ktg) * 512 + (q2 * 16 + quad * 4 + r) * 8 + j] =
                        (bf16_t)sfr[t8][mt][r];
        }
    }

    // ---- O = P V ----
    f32x4 oc[2][2] = {};
#pragma unroll
    for (int t8 = 0; t8 < 8; ++t8) {
        __syncthreads();  // sP complete (iter0); sKV reads of prev iter done
#pragma unroll
        for (int it = 0; it < 4; ++it) {
            const int c = w + it * 4;  // kt = c>>3, nt = c&7
            const int kt = c >> 3, nt = c & 7;
            gld16(sKV + c * 512,
                  vT + (size_t)((b * 16 + h) * 128 + nt * 16 + lm) * 512 + t8 * 64 + kt * 32 + quad * 8);
        }
        __syncthreads();
#pragma unroll
        for (int kt = 0; kt < 2; ++kt) {
            const int ktg = t8 * 2 + kt;
            bf16x8 a0 = *(const bf16x8*)(sP + ktg * 512 + l * 8);
            bf16x8 a1 = *(const bf16x8*)(sP + (16 + ktg) * 512 + l * 8);
#pragma unroll
            for (int ni = 0; ni < 2; ++ni) {
                bf16x8 bb = *(const bf16x8*)(sKV + (kt * 8 + w * 2 + ni) * 512 + l * 8);
                oc[0][ni] = __builtin_amdgcn_mfma_f32_16x16x32_bf16(a0, bb, oc[0][ni], 0, 0, 0);
                oc[1][ni] = __builtin_amdgcn_mfma_f32_16x16x32_bf16(a1, bb, oc[1][ni], 0, 0, 0);
            }
        }
    }

    // ---- epilogue: normalize rows, write o (bf16) ----
#pragma unroll
    for (int mt = 0; mt < 2; ++mt)
#pragma unroll
        for (int ni = 0; ni < 2; ++ni)
#pragma unroll
            for (int r = 0; r < 4; ++r) {
                const int row = mt * 16 + quad * 4 + r;
                const float v = oc[mt][ni][r] * inv[mt][r];
                obf[(size_t)(b * 4096 + n0 + row) * 2048 + h * 128 + w * 32 + ni * 16 + lm] =
                    (bf16_t)v;
            }
}

// ---------------------------------------------------------------------------
extern "C" void kernel_launch(void* const* d_in, const int* in_sizes, int n_in,
                              void* d_out, int out_size, void* d_ws, size_t ws_size,
                              hipStream_t stream) {
    (void)in_sizes; (void)n_in; (void)out_size; (void)ws_size;
    const float* x    = (const float*)d_in[0];  // [2,4096,2048]
    const float* cond = (const float*)d_in[1];  // [2,512,2048]
    const float* wq   = (const float*)d_in[2];  // [2048,2048]
    const float* bq   = (const float*)d_in[3];
    const float* wkv  = (const float*)d_in[4];  // [4096,2048]
    const float* bkv  = (const float*)d_in[5];
    const float* wp   = (const float*)d_in[6];  // [2048,2048]
    const float* bp   = (const float*)d_in[7];

    const size_t MB = 1ull << 20;
    uint8_t* ws = (uint8_t*)d_ws;
    bf16_t* qx    = (bf16_t*)(ws + 0);         // 32MB qdq(x); reused as o_bf
    bf16_t* qpj   = (bf16_t*)(ws + 32 * MB);   // 32MB q proj; reused as qdq(o)
    bf16_t* wqb   = (bf16_t*)(ws + 64 * MB);   // 8MB
    bf16_t* wkvb  = (bf16_t*)(ws + 72 * MB);   // 16MB
    bf16_t* wpb   = (bf16_t*)(ws + 88 * MB);   // 8MB
    bf16_t* condb = (bf16_t*)(ws + 96 * MB);   // 4MB
    bf16_t* kvb   = (bf16_t*)(ws + 100 * MB);  // 8MB
    bf16_t* vTb   = (bf16_t*)(ws + 108 * MB);  // 4MB  (total 112MB)

    dim3 blk(256);

    // 1. exact per-row fake-quant -> bf16
    quant_rows<float><<<8192, blk, 0, stream>>>(x, qx, 2048);
    quant_rows<float><<<2048, blk, 0, stream>>>(wq, wqb, 2048);
    quant_rows<float><<<2048, blk, 0, stream>>>(wp, wpb, 2048);
    // 2. plain bf16 converts
    cvt_bf16<<<2048, blk, 0, stream>>>((const float4*)cond, (bf16x4v*)condb, 524288);
    cvt_bf16<<<8192, blk, 0, stream>>>((const float4*)wkv, (bf16x4v*)wkvb, 2097152);
    // 3. q = qdq(x) qdq(wq)^T + bq   [8192 x 2048]
    gemm_bt<0><<<dim3(16, 64), blk, 0, stream>>>(qx, wqb, bq, qpj, 8192, 2048, 2048);
    // 4. kv = cond wkv^T + bkv       [1024 x 4096]
    gemm_bt<0><<<dim3(32, 8), blk, 0, stream>>>(condb, wkvb, bkv, kvb, 1024, 4096, 2048);
    // 5. V -> vT[(b*2048+c')*512 + m]
    transpose_v<<<dim3(64, 16, 2), blk, 0, stream>>>(kvb, vTb);
    // 6. fused attention -> o (bf16, reuses qx buffer)
    attn_kernel<<<dim3(128, 16, 2), blk, 0, stream>>>(qpj, kvb, vTb, qx);
    // 7. qdq(o) (reuses qpj buffer)
    quant_rows<bf16_t><<<8192, blk, 0, stream>>>(qx, qpj, 2048);
    // 8. out = qdq(o) qdq(wp)^T + bp  -> fp32 d_out
    gemm_bt<1><<<dim3(16, 64), blk, 0, stream>>>(qpj, wpb, bp, (float*)d_out, 8192, 2048, 2048);
}

// Round 2
// 599.381 us; speedup vs baseline: 1.2458x; 1.2458x over previous
//
#include <hip/hip_runtime.h>
#include <cstdint>
#include <cstddef>

// ---------------------------------------------------------------------------
// MultiHeadCrossAttention W8A8 fake-quant, MI355X (gfx950)
// B=2, N=4096, M=512, C=2048, H=16, Dh=128
//
// Everything staged via global_load_lds(16B) from PRE-PACKED fragment-stream
// layouts: each 1KB chunk is exactly one wave's gld16 (contiguous), so GEMM /
// attention staging is fully coalesced streaming. Packing is fused into the
// quant/convert passes and GEMM epilogues (which are scattered scalar stores
// anyway).
//
// GEMM-operand pack (M x K, 128-row panels, BK=32):
//   idx(row,col) = ((p*KT + kt)*8 + c)*512 + (quad*16 + lm)*8 + j
//   p=row>>7, c=(row>>4)&7, lm=row&15, kt=col>>5, quad=(col>>3)&3, j=col&7
// ---------------------------------------------------------------------------

typedef __bf16 bf16_t;
typedef __bf16 bf16x8 __attribute__((ext_vector_type(8)));
typedef float f32x4 __attribute__((ext_vector_type(4)));

__device__ __forceinline__ void gld16(void* lds, const void* g) {
    __builtin_amdgcn_global_load_lds(
        (__attribute__((address_space(1))) uint32_t*)(uintptr_t)g,
        (__attribute__((address_space(3))) uint32_t*)(uint32_t)(uintptr_t)lds,
        16, 0, 0);
}

__device__ __forceinline__ void load8(const float* p, int i, float* v) {
    const float4* p4 = (const float4*)p;
    float4 a = p4[2 * i], b = p4[2 * i + 1];
    v[0] = a.x; v[1] = a.y; v[2] = a.z; v[3] = a.w;
    v[4] = b.x; v[5] = b.y; v[6] = b.z; v[7] = b.w;
}
__device__ __forceinline__ void load8(const bf16_t* p, int i, float* v) {
    bf16x8 t = ((const bf16x8*)p)[i];
#pragma unroll
    for (int j = 0; j < 8; ++j) v[j] = (float)t[j];
}

// ---------------------------------------------------------------------------
// Per-row fake-quant (QUANT=1) or plain convert (QUANT=0), output packed.
// One block per row; vectorized 8-wide loads; 16B packed stores.
// ---------------------------------------------------------------------------
template <int QUANT, typename T>
__global__ __launch_bounds__(256) void rowpack(const T* __restrict__ in,
                                               bf16_t* __restrict__ out, int K) {
    const int tid = threadIdx.x;
    const size_t row = blockIdx.x;
    const T* rp = in + row * (size_t)K;
    const int n8 = K >> 3;
    float scale = 1.0f;
    if (QUANT) {
        float m = 0.f;
        for (int i = tid; i < n8; i += 256) {
            float v[8];
            load8(rp, i, v);
#pragma unroll
            for (int j = 0; j < 8; ++j) m = fmaxf(m, fabsf(v[j]));
        }
        __shared__ float red[256];
        red[tid] = m;
        __syncthreads();
        for (int s = 128; s > 0; s >>= 1) {
            if (tid < s) red[tid] = fmaxf(red[tid], red[tid + s]);
            __syncthreads();
        }
        scale = fmaxf(red[0] * (1.0f / 127.0f), 1e-8f);
    }
    const int KT = K >> 5;
    const int p = (int)(row >> 7), c = ((int)row >> 4) & 7, lm = (int)row & 15;
    for (int i = tid; i < n8; i += 256) {
        const int col = i << 3;
        const int kt = col >> 5, quad = (col >> 3) & 3;
        float v[8];
        load8(rp, i, v);
        bf16x8 o8;
#pragma unroll
        for (int j = 0; j < 8; ++j) {
            float q = v[j];
            if (QUANT) {
                q = rintf(q / scale);  // RNE, matches jnp.round
                q = fminf(127.f, fmaxf(-127.f, q)) * scale;
            }
            o8[j] = (bf16_t)q;
        }
        const size_t dst = ((size_t)(p * KT + kt) * 8 + c) * 512 + (quad * 16 + lm) * 8;
        *(bf16x8*)(out + dst) = o8;
    }
}

// ---------------------------------------------------------------------------
// GEMM on packed operands: C[M x N] = A Bt^T + bias.
// 128x128 tile, BK=32, 4 waves (2x2), mfma 16x16x32 bf16.
// MODE 0: out -> attention-packed q.  MODE 1: natural fp32.  MODE 2: kv split
//         into packed K (S-phase B-frags) + packed V (PV-phase B-frags).
// ---------------------------------------------------------------------------
template <int MODE>
__global__ __launch_bounds__(256) void gemm_pk(const bf16_t* __restrict__ A,
                                               const bf16_t* __restrict__ B,
                                               const float* __restrict__ bias,
                                               void* __restrict__ C,
                                               int N, int K) {
    __shared__ __align__(16) bf16_t sA[4096];
    __shared__ __align__(16) bf16_t sB[4096];

    const int tid = threadIdx.x;
    const int l = tid & 63, w = tid >> 6;
    const int lm = l & 15, quad = l >> 4;
    const int wm = w & 1, wn = w >> 1;
    const int KT = K >> 5;
    const size_t aBase = (size_t)blockIdx.y * KT * 8 * 512;
    const size_t bBase = (size_t)blockIdx.x * KT * 8 * 512;

    f32x4 acc[4][4] = {};
    for (int kt = 0; kt < KT; ++kt) {
        __syncthreads();
#pragma unroll
        for (int it = 0; it < 2; ++it) {
            const int c = w + it * 4;  // wave-uniform chunk id
            gld16(sA + c * 512, A + aBase + ((size_t)kt * 8 + c) * 512 + l * 8);
            gld16(sB + c * 512, B + bBase + ((size_t)kt * 8 + c) * 512 + l * 8);
        }
        __syncthreads();
        bf16x8 af[4], bfr[4];
#pragma unroll
        for (int i = 0; i < 4; ++i)
            af[i] = *(const bf16x8*)(sA + (wm * 4 + i) * 512 + l * 8);
#pragma unroll
        for (int j = 0; j < 4; ++j)
            bfr[j] = *(const bf16x8*)(sB + (wn * 4 + j) * 512 + l * 8);
#pragma unroll
        for (int i = 0; i < 4; ++i)
#pragma unroll
            for (int j = 0; j < 4; ++j)
                acc[i][j] = __builtin_amdgcn_mfma_f32_16x16x32_bf16(af[i], bfr[j], acc[i][j], 0, 0, 0);
    }
    // C/D layout: row = quad*4+r, col = lane&15
#pragma unroll
    for (int i = 0; i < 4; ++i) {
#pragma unroll
        for (int j = 0; j < 4; ++j) {
            const int col = blockIdx.x * 128 + wn * 64 + j * 16 + lm;
            const float bv = bias[col];
#pragma unroll
            for (int r = 0; r < 4; ++r) {
                const int row = blockIdx.y * 128 + wm * 64 + i * 16 + quad * 4 + r;
                const float v = acc[i][j][r] + bv;
                if (MODE == 1) {
                    ((float*)C)[(size_t)row * N + col] = v;
                } else if (MODE == 0) {
                    // q -> attention A-frag pack: (b,h,p64,kt,mt) chunks
                    const int b = row >> 12, n = row & 4095;
                    const int h = col >> 7, d = col & 127;
                    const int p = n >> 6, mt = (n >> 4) & 3, lmq = n & 15;
                    const int kq = d >> 5, qq = (d >> 3) & 3, jq = d & 7;
                    const size_t idx =
                        (((size_t)(b * 16 + h) * 64 + p) * 16 + kq * 4 + mt) * 512 +
                        (qq * 16 + lmq) * 8 + jq;
                    ((bf16_t*)C)[idx] = (bf16_t)v;
                } else {
                    // kv split: K-half -> S-phase B-frags, V-half -> PV B-frags
                    const int b = row >> 9, m = row & 511;
                    const int half = col >> 11, h = (col >> 7) & 15, d = col & 127;
                    const int t8 = m >> 6;
                    bf16_t* out = (bf16_t*)C;
                    if (half == 0) {
                        const int nt = (m >> 4) & 3, lmk = m & 15;
                        const int kc = d >> 5, qk = (d >> 3) & 3, jk = d & 7;
                        const size_t idx =
                            (((size_t)(b * 16 + h) * 8 + t8) * 16 + kc * 4 + nt) * 512 +
                            (qk * 16 + lmk) * 8 + jk;
                        out[idx] = (bf16_t)v;
                    } else {
                        const int kv2 = (m >> 5) & 1, qv = (m >> 3) & 3, jv = m & 7;
                        const int ntv = d >> 4, lmv = d & 15;
                        const size_t idx = 2097152 +
                            (((size_t)(b * 16 + h) * 8 + t8) * 16 + kv2 * 8 + ntv) * 512 +
                            (qv * 16 + lmv) * 8 + jv;
                        out[idx] = (bf16_t)v;
                    }
                }
            }
        }
    }
}

// ---------------------------------------------------------------------------
// Fused attention, 64 q-rows per block. S register-resident (128 VGPR),
// full softmax, P -> small LDS buffer per 64-key group, PV via MFMA.
// All staging contiguous from packed q / K / V.
// ---------------------------------------------------------------------------
__global__ __launch_bounds__(256, 2) void attn64(const bf16_t* __restrict__ qpk,
                                                 const bf16_t* __restrict__ kvpk,
                                                 bf16_t* __restrict__ o) {
    constexpr float SCALE = 0.08838834764831845f;  // 1/sqrt(128)
    __shared__ __align__(16) bf16_t sQ[8192];   // 16KB: chunks kt*4+mt
    __shared__ __align__(16) bf16_t sKV[8192];  // 16KB: K chunks kc*4+nt / V chunks kv*8+nt
    __shared__ __align__(16) bf16_t sP[4096];   // 8KB : chunks mt*2+ktv
    __shared__ float redM[4][64];
    __shared__ float redS[4][64];

    const int tid = threadIdx.x;
    const int l = tid & 63, w = tid >> 6;
    const int lm = l & 15, quad = l >> 4;
    const int b = blockIdx.z, h = blockIdx.y;
    const int p = blockIdx.x;                   // 64-row q panel
    const int bh = b * 16 + h;
    const size_t qbase = ((size_t)bh * 64 + p) * 8192;
    const size_t kbase = (size_t)bh * 65536;
    const size_t vbase = 2097152 + (size_t)bh * 65536;

    // ---- stage Q [64 x 128] ----
#pragma unroll
    for (int it = 0; it < 4; ++it) {
        const int c = it * 4 + w;
        gld16(sQ + c * 512, qpk + qbase + (size_t)c * 512 + l * 8);
    }

    // ---- S = Q K^T over 8 key-groups of 64 ----
    f32x4 sfr[8][4] = {};
#pragma unroll
    for (int t8 = 0; t8 < 8; ++t8) {
        __syncthreads();
#pragma unroll
        for (int it = 0; it < 4; ++it) {
            const int c = it * 4 + w;
            gld16(sKV + c * 512, kvpk + kbase + ((size_t)t8 * 16 + c) * 512 + l * 8);
        }
        __syncthreads();
#pragma unroll
        for (int kc = 0; kc < 4; ++kc) {
            bf16x8 bb = *(const bf16x8*)(sKV + (kc * 4 + w) * 512 + l * 8);
#pragma unroll
            for (int mt = 0; mt < 4; ++mt) {
                bf16x8 aa = *(const bf16x8*)(sQ + (kc * 4 + mt) * 512 + l * 8);
                sfr[t8][mt] = __builtin_amdgcn_mfma_f32_16x16x32_bf16(aa, bb, sfr[t8][mt], 0, 0, 0);
            }
        }
    }

    // ---- softmax: lane holds rows mt*16+quad*4+r, cols t8*64 + w*16 + lm ----
    float inv[4][4];
    {
        float mymax[4][4];
#pragma unroll
        for (int mt = 0; mt < 4; ++mt)
#pragma unroll
            for (int r = 0; r < 4; ++r) {
                float m = -3.0e38f;
#pragma unroll
                for (int t8 = 0; t8 < 8; ++t8) m = fmaxf(m, sfr[t8][mt][r]);
                m = fmaxf(m, __shfl_xor(m, 1));
                m = fmaxf(m, __shfl_xor(m, 2));
                m = fmaxf(m, __shfl_xor(m, 4));
                m = fmaxf(m, __shfl_xor(m, 8));
                mymax[mt][r] = m;
            }
        if (lm == 0) {
#pragma unroll
            for (int mt = 0; mt < 4; ++mt)
#pragma unroll
                for (int r = 0; r < 4; ++r)
                    redM[w][mt * 16 + quad * 4 + r] = mymax[mt][r];
        }
        __syncthreads();
#pragma unroll
        for (int mt = 0; mt < 4; ++mt)
#pragma unroll
            for (int r = 0; r < 4; ++r) {
                const int row = mt * 16 + quad * 4 + r;
                const float M =
                    fmaxf(fmaxf(redM[0][row], redM[1][row]), fmaxf(redM[2][row], redM[3][row])) *
                    SCALE;
                float s = 0.f;
#pragma unroll
                for (int t8 = 0; t8 < 8; ++t8) {
                    const float pe = __expf(sfr[t8][mt][r] * SCALE - M);
                    sfr[t8][mt][r] = pe;
                    s += pe;
                }
                s += __shfl_xor(s, 1);
                s += __shfl_xor(s, 2);
                s += __shfl_xor(s, 4);
                s += __shfl_xor(s, 8);
                if (lm == 0) redS[w][row] = s;
            }
        __syncthreads();
#pragma unroll
        for (int mt = 0; mt < 4; ++mt)
#pragma unroll
            for (int r = 0; r < 4; ++r) {
                const int row = mt * 16 + quad * 4 + r;
                inv[mt][r] = 1.f / (redS[0][row] + redS[1][row] + redS[2][row] + redS[3][row]);
            }
    }

    // ---- O = P V ----
    f32x4 oc[4][2] = {};
    const int ktd = w >> 1;
    const int quadd = (w & 1) * 2 + (lm >> 3);
    const int jd = lm & 7;
#pragma unroll
    for (int t8 = 0; t8 < 8; ++t8) {
        __syncthreads();  // prev iter's sP/sKV reads done (also S-phase reads)
#pragma unroll
        for (int mt = 0; mt < 4; ++mt)
#pragma unroll
            for (int r = 0; r < 4; ++r)
                sP[(mt * 2 + ktd) * 512 + (quadd * 16 + quad * 4 + r) * 8 + jd] =
                    (bf16_t)sfr[t8][mt][r];
#pragma unroll
        for (int it = 0; it < 4; ++it) {
            const int c = it * 4 + w;
            gld16(sKV + c * 512, kvpk + vbase + ((size_t)t8 * 16 + c) * 512 + l * 8);
        }
        __syncthreads();  // drains vmcnt(0); sP visible
#pragma unroll
        for (int kv = 0; kv < 2; ++kv) {
            bf16x8 aa[4];
#pragma unroll
            for (int mt = 0; mt < 4; ++mt)
                aa[mt] = *(const bf16x8*)(sP + (mt * 2 + kv) * 512 + l * 8);
#pragma unroll
            for (int ni = 0; ni < 2; ++ni) {
                bf16x8 bb = *(const bf16x8*)(sKV + (kv * 8 + w * 2 + ni) * 512 + l * 8);
#pragma unroll
                for (int mt = 0; mt < 4; ++mt)
                    oc[mt][ni] = __builtin_amdgcn_mfma_f32_16x16x32_bf16(aa[mt], bb, oc[mt][ni], 0, 0, 0);
            }
        }
    }

    // ---- epilogue: normalize, write natural-layout o ----
#pragma unroll
    for (int mt = 0; mt < 4; ++mt)
#pragma unroll
        for (int ni = 0; ni < 2; ++ni)
#pragma unroll
            for (int r = 0; r < 4; ++r) {
                const int row = mt * 16 + quad * 4 + r;
                const int d = w * 32 + ni * 16 + lm;
                o[((size_t)b * 4096 + p * 64 + row) * 2048 + h * 128 + d] =
                    (bf16_t)(oc[mt][ni][r] * inv[mt][r]);
            }
}

// ---------------------------------------------------------------------------
extern "C" void kernel_launch(void* const* d_in, const int* in_sizes, int n_in,
                              void* d_out, int out_size, void* d_ws, size_t ws_size,
                              hipStream_t stream) {
    (void)in_sizes; (void)n_in; (void)out_size; (void)ws_size;
    const float* x    = (const float*)d_in[0];
    const float* cond = (const float*)d_in[1];
    const float* wq   = (const float*)d_in[2];
    const float* bq   = (const float*)d_in[3];
    const float* wkv  = (const float*)d_in[4];
    const float* bkv  = (const float*)d_in[5];
    const float* wp   = (const float*)d_in[6];
    const float* bp   = (const float*)d_in[7];

    const size_t MB = 1ull << 20;
    uint8_t* ws = (uint8_t*)d_ws;
    bf16_t* qxpk   = (bf16_t*)(ws + 0);        // 32MB qdq(x) packed; reused as o natural
    bf16_t* qpk    = (bf16_t*)(ws + 32 * MB);  // 32MB q packed; reused as qdq(o) packed
    bf16_t* wqpk   = (bf16_t*)(ws + 64 * MB);  // 8MB
    bf16_t* wkvpk  = (bf16_t*)(ws + 72 * MB);  // 16MB
    bf16_t* wppk   = (bf16_t*)(ws + 88 * MB);  // 8MB
    bf16_t* condpk = (bf16_t*)(ws + 96 * MB);  // 4MB
    bf16_t* kvpk   = (bf16_t*)(ws + 100 * MB); // 8MB (K 4MB | V 4MB)
    bf16_t* o_nat  = qxpk;
    bf16_t* opk    = qpk;

    dim3 blk(256);
    // quant / convert + pack
    rowpack<1, float><<<8192, blk, 0, stream>>>(x, qxpk, 2048);
    rowpack<1, float><<<2048, blk, 0, stream>>>(wq, wqpk, 2048);
    rowpack<1, float><<<2048, blk, 0, stream>>>(wp, wppk, 2048);
    rowpack<0, float><<<1024, blk, 0, stream>>>(cond, condpk, 2048);
    rowpack<0, float><<<4096, blk, 0, stream>>>(wkv, wkvpk, 2048);
    // q = qdq(x) qdq(wq)^T + bq  -> attention-packed
    gemm_pk<0><<<dim3(16, 64), blk, 0, stream>>>(qxpk, wqpk, bq, qpk, 2048, 2048);
    // kv = cond wkv^T + bkv      -> packed K | packed V
    gemm_pk<2><<<dim3(32, 8), blk, 0, stream>>>(condpk, wkvpk, bkv, kvpk, 4096, 2048);
    // attention -> o natural (reuses qxpk region)
    attn64<<<dim3(64, 16, 2), blk, 0, stream>>>(qpk, kvpk, o_nat);
    // qdq(o) packed (reuses qpk region)
    rowpack<1, bf16_t><<<8192, blk, 0, stream>>>(o_nat, opk, 2048);
    // out = qdq(o) qdq(wp)^T + bp -> natural fp32
    gemm_pk<1><<<dim3(16, 64), blk, 0, stream>>>(opk, wppk, bp, (float*)d_out, 2048, 2048);
}

// Round 3
// 534.473 us; speedup vs baseline: 1.3971x; 1.1214x over previous
//
#include <hip/hip_runtime.h>
#include <cstdint>
#include <cstddef>

// ---------------------------------------------------------------------------
// MultiHeadCrossAttention W8A8 fake-quant, MI355X (gfx950)
// B=2, N=4096, M=512, C=2048, H=16, Dh=128
//
// All MFMA inputs staged via global_load_lds(16B) from PRE-PACKED
// fragment-stream layouts (each 1KB chunk = one wave gld16, contiguous).
// R3: BK=64 K-loops (half the barrier crossings), 64-row tiles for the kv
// GEMM (2 blocks/CU instead of 1), 128-key attention groups with sP aliasing
// sQ (LDS 50KB -> 3 blocks/CU).
//
// GEMM-operand pack (M x K, 128-row panels, 32-col chunk groups):
//   idx(row,col) = ((p*KT + kt)*8 + c)*512 + (quad*16 + lm)*8 + j
//   p=row>>7, c=(row>>4)&7, lm=row&15, kt=col>>5, quad=(col>>3)&3, j=col&7
// ---------------------------------------------------------------------------

typedef __bf16 bf16_t;
typedef __bf16 bf16x8 __attribute__((ext_vector_type(8)));
typedef float f32x4 __attribute__((ext_vector_type(4)));

__device__ __forceinline__ void gld16(void* lds, const void* g) {
    __builtin_amdgcn_global_load_lds(
        (__attribute__((address_space(1))) uint32_t*)(uintptr_t)g,
        (__attribute__((address_space(3))) uint32_t*)(uint32_t)(uintptr_t)lds,
        16, 0, 0);
}

__device__ __forceinline__ void load8(const float* p, int i, float* v) {
    const float4* p4 = (const float4*)p;
    float4 a = p4[2 * i], b = p4[2 * i + 1];
    v[0] = a.x; v[1] = a.y; v[2] = a.z; v[3] = a.w;
    v[4] = b.x; v[5] = b.y; v[6] = b.z; v[7] = b.w;
}
__device__ __forceinline__ void load8(const bf16_t* p, int i, float* v) {
    bf16x8 t = ((const bf16x8*)p)[i];
#pragma unroll
    for (int j = 0; j < 8; ++j) v[j] = (float)t[j];
}

// ---------------------------------------------------------------------------
// Per-row fake-quant (QUANT=1) or plain convert (QUANT=0), output packed.
// ---------------------------------------------------------------------------
template <int QUANT, typename T>
__global__ __launch_bounds__(256) void rowpack(const T* __restrict__ in,
                                               bf16_t* __restrict__ out, int K) {
    const int tid = threadIdx.x;
    const size_t row = blockIdx.x;
    const T* rp = in + row * (size_t)K;
    const int n8 = K >> 3;
    float scale = 1.0f;
    if (QUANT) {
        float m = 0.f;
        for (int i = tid; i < n8; i += 256) {
            float v[8];
            load8(rp, i, v);
#pragma unroll
            for (int j = 0; j < 8; ++j) m = fmaxf(m, fabsf(v[j]));
        }
        __shared__ float red[256];
        red[tid] = m;
        __syncthreads();
        for (int s = 128; s > 0; s >>= 1) {
            if (tid < s) red[tid] = fmaxf(red[tid], red[tid + s]);
            __syncthreads();
        }
        scale = fmaxf(red[0] * (1.0f / 127.0f), 1e-8f);
    }
    const int KT = K >> 5;
    const int p = (int)(row >> 7), c = ((int)row >> 4) & 7, lm = (int)row & 15;
    for (int i = tid; i < n8; i += 256) {
        const int col = i << 3;
        const int kt = col >> 5, quad = (col >> 3) & 3;
        float v[8];
        load8(rp, i, v);
        bf16x8 o8;
#pragma unroll
        for (int j = 0; j < 8; ++j) {
            float q = v[j];
            if (QUANT) {
                q = rintf(q / scale);  // RNE, matches jnp.round
                q = fminf(127.f, fmaxf(-127.f, q)) * scale;
            }
            o8[j] = (bf16_t)q;
        }
        const size_t dst = ((size_t)(p * KT + kt) * 8 + c) * 512 + (quad * 16 + lm) * 8;
        *(bf16x8*)(out + dst) = o8;
    }
}

// ---------------------------------------------------------------------------
// Epilogue stores (shared by the GEMM kernels).
// MODE 0: attention-packed q.  MODE 1: natural fp32.  MODE 2: kv split pack.
// ---------------------------------------------------------------------------
template <int MODE>
__device__ __forceinline__ void epi_store(void* C, int N, int row, int col, float v) {
    if (MODE == 1) {
        ((float*)C)[(size_t)row * N + col] = v;
    } else if (MODE == 0) {
        const int b = row >> 12, n = row & 4095;
        const int h = col >> 7, d = col & 127;
        const int p = n >> 6, mt = (n >> 4) & 3, lmq = n & 15;
        const int kq = d >> 5, qq = (d >> 3) & 3, jq = d & 7;
        const size_t idx = (((size_t)(b * 16 + h) * 64 + p) * 16 + kq * 4 + mt) * 512 +
                           (qq * 16 + lmq) * 8 + jq;
        ((bf16_t*)C)[idx] = (bf16_t)v;
    } else {
        const int b = row >> 9, m = row & 511;
        const int half = col >> 11, h = (col >> 7) & 15, d = col & 127;
        const int t8 = m >> 6;
        bf16_t* out = (bf16_t*)C;
        if (half == 0) {
            const int nt = (m >> 4) & 3, lmk = m & 15;
            const int kc = d >> 5, qk = (d >> 3) & 3, jk = d & 7;
            const size_t idx = (((size_t)(b * 16 + h) * 8 + t8) * 16 + kc * 4 + nt) * 512 +
                               (qk * 16 + lmk) * 8 + jk;
            out[idx] = (bf16_t)v;
        } else {
            const int kv2 = (m >> 5) & 1, qv = (m >> 3) & 3, jv = m & 7;
            const int ntv = d >> 4, lmv = d & 15;
            const size_t idx = 2097152 +
                (((size_t)(b * 16 + h) * 8 + t8) * 16 + kv2 * 8 + ntv) * 512 +
                (qv * 16 + lmv) * 8 + jv;
            out[idx] = (bf16_t)v;
        }
    }
}

// ---------------------------------------------------------------------------
// GEMM on packed operands: C[M x N] = A B^T + bias.  128x128 tile, BK=64,
// 4 waves (2x2), mfma 16x16x32 bf16.  32 MFMA per barrier-pair.
// ---------------------------------------------------------------------------
template <int MODE>
__global__ __launch_bounds__(256) void gemm_pk(const bf16_t* __restrict__ A,
                                               const bf16_t* __restrict__ B,
                                               const float* __restrict__ bias,
                                               void* __restrict__ C,
                                               int N, int K) {
    __shared__ __align__(16) bf16_t sA[8192];  // 16KB = 16 chunks
    __shared__ __align__(16) bf16_t sB[8192];

    const int tid = threadIdx.x;
    const int l = tid & 63, w = tid >> 6;
    const int lm = l & 15, quad = l >> 4;
    const int wm = w & 1, wn = w >> 1;
    const int KT = K >> 5;
    const size_t aBase = (size_t)blockIdx.y * KT * 8 * 512;
    const size_t bBase = (size_t)blockIdx.x * KT * 8 * 512;

    f32x4 acc[4][4] = {};
    const int NIT = K >> 6;
    for (int kt = 0; kt < NIT; ++kt) {
        __syncthreads();
#pragma unroll
        for (int it = 0; it < 4; ++it) {
            const int c = it * 4 + w;  // 0..15, wave-uniform
            gld16(sA + c * 512, A + aBase + ((size_t)kt * 16 + c) * 512 + l * 8);
            gld16(sB + c * 512, B + bBase + ((size_t)kt * 16 + c) * 512 + l * 8);
        }
        __syncthreads();
#pragma unroll
        for (int h = 0; h < 2; ++h) {
            bf16x8 af[4], bfr[4];
#pragma unroll
            for (int i = 0; i < 4; ++i)
                af[i] = *(const bf16x8*)(sA + (h * 8 + wm * 4 + i) * 512 + l * 8);
#pragma unroll
            for (int j = 0; j < 4; ++j)
                bfr[j] = *(const bf16x8*)(sB + (h * 8 + wn * 4 + j) * 512 + l * 8);
#pragma unroll
            for (int i = 0; i < 4; ++i)
#pragma unroll
                for (int j = 0; j < 4; ++j)
                    acc[i][j] =
                        __builtin_amdgcn_mfma_f32_16x16x32_bf16(af[i], bfr[j], acc[i][j], 0, 0, 0);
        }
    }
#pragma unroll
    for (int i = 0; i < 4; ++i) {
#pragma unroll
        for (int j = 0; j < 4; ++j) {
            const int col = blockIdx.x * 128 + wn * 64 + j * 16 + lm;
            const float bv = bias[col];
#pragma unroll
            for (int r = 0; r < 4; ++r) {
                const int row = blockIdx.y * 128 + wm * 64 + i * 16 + quad * 4 + r;
                epi_store<MODE>(C, N, row, col, acc[i][j][r] + bv);
            }
        }
    }
}

// ---------------------------------------------------------------------------
// kv GEMM: 64x128 tile, BK=64, 4 waves (2x2: wave = 32 rows x 64 cols).
// 512 blocks -> 2 blocks/CU.  Epilogue: MODE2 kv split pack.
// ---------------------------------------------------------------------------
__global__ __launch_bounds__(256) void gemm_kv(const bf16_t* __restrict__ A,
                                               const bf16_t* __restrict__ B,
                                               const float* __restrict__ bias,
                                               bf16_t* __restrict__ C,
                                               int N, int K) {
    __shared__ __align__(16) bf16_t sA[4096];  // 8 chunks (64 rows x 64 k)
    __shared__ __align__(16) bf16_t sB[8192];  // 16 chunks

    const int tid = threadIdx.x;
    const int l = tid & 63, w = tid >> 6;
    const int lm = l & 15, quad = l >> 4;
    const int wm = w & 1, wn = w >> 1;
    const int KT = K >> 5;
    const int p = blockIdx.y >> 1, hh = blockIdx.y & 1;  // 64-row half of 128-panel
    const size_t aPan = (size_t)p * KT * 8 * 512;
    const size_t bBase = (size_t)blockIdx.x * KT * 8 * 512;

    f32x4 acc[2][4] = {};
    const int NIT = K >> 6;
    for (int kt = 0; kt < NIT; ++kt) {
        __syncthreads();
#pragma unroll
        for (int it = 0; it < 2; ++it) {
            const int lc = it * 4 + w;  // 0..7
            const int s = lc >> 2, cc = lc & 3;
            gld16(sA + lc * 512,
                  A + aPan + ((size_t)(kt * 2 + s) * 8 + hh * 4 + cc) * 512 + l * 8);
        }
#pragma unroll
        for (int it = 0; it < 4; ++it) {
            const int lc = it * 4 + w;  // 0..15
            gld16(sB + lc * 512, B + bBase + ((size_t)kt * 16 + lc) * 512 + l * 8);
        }
        __syncthreads();
#pragma unroll
        for (int s = 0; s < 2; ++s) {
            bf16x8 af[2], bfr[4];
#pragma unroll
            for (int i = 0; i < 2; ++i)
                af[i] = *(const bf16x8*)(sA + (s * 4 + wm * 2 + i) * 512 + l * 8);
#pragma unroll
            for (int j = 0; j < 4; ++j)
                bfr[j] = *(const bf16x8*)(sB + (s * 8 + wn * 4 + j) * 512 + l * 8);
#pragma unroll
            for (int i = 0; i < 2; ++i)
#pragma unroll
                for (int j = 0; j < 4; ++j)
                    acc[i][j] =
                        __builtin_amdgcn_mfma_f32_16x16x32_bf16(af[i], bfr[j], acc[i][j], 0, 0, 0);
        }
    }
#pragma unroll
    for (int i = 0; i < 2; ++i) {
#pragma unroll
        for (int j = 0; j < 4; ++j) {
            const int col = blockIdx.x * 128 + wn * 64 + j * 16 + lm;
            const float bv = bias[col];
#pragma unroll
            for (int r = 0; r < 4; ++r) {
                const int row = blockIdx.y * 64 + wm * 32 + i * 16 + quad * 4 + r;
                epi_store<2>(C, N, row, col, acc[i][j][r] + bv);
            }
        }
    }
}

// ---------------------------------------------------------------------------
// Fused attention, 64 q-rows per block, 128-key staging groups.
// S register-resident (128 VGPR), sP aliases sQ (Q dead after S-phase).
// LDS: 16 + 32 + 2 = 50KB -> 3 blocks/CU ceiling.
// ---------------------------------------------------------------------------
__global__ __launch_bounds__(256, 2) void attn64(const bf16_t* __restrict__ qpk,
                                                 const bf16_t* __restrict__ kvpk,
                                                 bf16_t* __restrict__ o) {
    constexpr float SCALE = 0.08838834764831845f;  // 1/sqrt(128)
    __shared__ __align__(16) bf16_t sQP[8192];   // 16KB: Q chunks kc*4+mt, then P chunks mt*4+kv
    __shared__ __align__(16) bf16_t sKV[16384];  // 32KB: 32 chunks per 128-key group
    __shared__ float redM[4][64];
    __shared__ float redS[4][64];

    const int tid = threadIdx.x;
    const int l = tid & 63, w = tid >> 6;
    const int lm = l & 15, quad = l >> 4;
    const int b = blockIdx.z, h = blockIdx.y;
    const int p = blockIdx.x;  // 64-row q panel
    const int bh = b * 16 + h;
    const size_t qbase = ((size_t)bh * 64 + p) * 8192;
    const size_t kbase = (size_t)bh * 65536;
    const size_t vbase = 2097152 + (size_t)bh * 65536;

    // ---- stage Q [64 x 128] ----
#pragma unroll
    for (int it = 0; it < 4; ++it) {
        const int c = it * 4 + w;
        gld16(sQP + c * 512, qpk + qbase + (size_t)c * 512 + l * 8);
    }

    // ---- S = Q K^T over 4 key-groups of 128 ----
    f32x4 sfr[8][4] = {};
#pragma unroll
    for (int g = 0; g < 4; ++g) {
        __syncthreads();
#pragma unroll
        for (int it = 0; it < 8; ++it) {
            const int c = it * 4 + w;  // 0..31
            gld16(sKV + c * 512, kvpk + kbase + ((size_t)g * 32 + c) * 512 + l * 8);
        }
        __syncthreads();
#pragma unroll
        for (int kc = 0; kc < 4; ++kc) {
#pragma unroll
            for (int kk = 0; kk < 2; ++kk) {
                bf16x8 bb = *(const bf16x8*)(sKV + (kk * 16 + kc * 4 + w) * 512 + l * 8);
#pragma unroll
                for (int mt = 0; mt < 4; ++mt) {
                    bf16x8 aa = *(const bf16x8*)(sQP + (kc * 4 + mt) * 512 + l * 8);
                    sfr[g * 2 + kk][mt] =
                        __builtin_amdgcn_mfma_f32_16x16x32_bf16(aa, bb, sfr[g * 2 + kk][mt], 0, 0, 0);
                }
            }
        }
    }

    // ---- softmax: lane holds rows mt*16+quad*4+r, cols t8*64 + w*16 + lm ----
    float inv[4][4];
    {
        float mymax[4][4];
#pragma unroll
        for (int mt = 0; mt < 4; ++mt)
#pragma unroll
            for (int r = 0; r < 4; ++r) {
                float m = -3.0e38f;
#pragma unroll
                for (int t8 = 0; t8 < 8; ++t8) m = fmaxf(m, sfr[t8][mt][r]);
                m = fmaxf(m, __shfl_xor(m, 1));
                m = fmaxf(m, __shfl_xor(m, 2));
                m = fmaxf(m, __shfl_xor(m, 4));
                m = fmaxf(m, __shfl_xor(m, 8));
                mymax[mt][r] = m;
            }
        if (lm == 0) {
#pragma unroll
            for (int mt = 0; mt < 4; ++mt)
#pragma unroll
                for (int r = 0; r < 4; ++r)
                    redM[w][mt * 16 + quad * 4 + r] = mymax[mt][r];
        }
        __syncthreads();
#pragma unroll
        for (int mt = 0; mt < 4; ++mt)
#pragma unroll
            for (int r = 0; r < 4; ++r) {
                const int row = mt * 16 + quad * 4 + r;
                const float M =
                    fmaxf(fmaxf(redM[0][row], redM[1][row]), fmaxf(redM[2][row], redM[3][row])) *
                    SCALE;
                float s = 0.f;
#pragma unroll
                for (int t8 = 0; t8 < 8; ++t8) {
                    const float pe = __expf(sfr[t8][mt][r] * SCALE - M);
                    sfr[t8][mt][r] = pe;
                    s += pe;
                }
                s += __shfl_xor(s, 1);
                s += __shfl_xor(s, 2);
                s += __shfl_xor(s, 4);
                s += __shfl_xor(s, 8);
                if (lm == 0) redS[w][row] = s;
            }
        __syncthreads();
#pragma unroll
        for (int mt = 0; mt < 4; ++mt)
#pragma unroll
            for (int r = 0; r < 4; ++r) {
                const int row = mt * 16 + quad * 4 + r;
                inv[mt][r] = 1.f / (redS[0][row] + redS[1][row] + redS[2][row] + redS[3][row]);
            }
    }

    // ---- O = P V over 4 key-groups of 128 ----
    f32x4 oc[4][2] = {};
    const int ktd = w >> 1;
    const int quadd = (w & 1) * 2 + (lm >> 3);
    const int jd = lm & 7;
#pragma unroll
    for (int g = 0; g < 4; ++g) {
        __syncthreads();  // prev iter's sQP/sKV reads done; S-phase reads done (g=0)
#pragma unroll
        for (int kk = 0; kk < 2; ++kk)
#pragma unroll
            for (int mt = 0; mt < 4; ++mt)
#pragma unroll
                for (int r = 0; r < 4; ++r)
                    sQP[(mt * 4 + kk * 2 + ktd) * 512 + (quadd * 16 + quad * 4 + r) * 8 + jd] =
                        (bf16_t)sfr[g * 2 + kk][mt][r];
#pragma unroll
        for (int it = 0; it < 8; ++it) {
            const int c = it * 4 + w;  // 0..31
            gld16(sKV + c * 512, kvpk + vbase + ((size_t)g * 32 + c) * 512 + l * 8);
        }
        __syncthreads();  // drains vmcnt(0); sQP(P) visible
#pragma unroll
        for (int kvf = 0; kvf < 4; ++kvf) {
            const int kk = kvf >> 1, kv2 = kvf & 1;
            bf16x8 aa[4];
#pragma unroll
            for (int mt = 0; mt < 4; ++mt)
                aa[mt] = *(const bf16x8*)(sQP + (mt * 4 + kvf) * 512 + l * 8);
#pragma unroll
            for (int ni = 0; ni < 2; ++ni) {
                bf16x8 bb =
                    *(const bf16x8*)(sKV + (kk * 16 + kv2 * 8 + w * 2 + ni) * 512 + l * 8);
#pragma unroll
                for (int mt = 0; mt < 4; ++mt)
                    oc[mt][ni] =
                        __builtin_amdgcn_mfma_f32_16x16x32_bf16(aa[mt], bb, oc[mt][ni], 0, 0, 0);
            }
        }
    }

    // ---- epilogue: normalize, write natural-layout o ----
#pragma unroll
    for (int mt = 0; mt < 4; ++mt)
#pragma unroll
        for (int ni = 0; ni < 2; ++ni)
#pragma unroll
            for (int r = 0; r < 4; ++r) {
                const int row = mt * 16 + quad * 4 + r;
                const int d = w * 32 + ni * 16 + lm;
                o[((size_t)b * 4096 + p * 64 + row) * 2048 + h * 128 + d] =
                    (bf16_t)(oc[mt][ni][r] * inv[mt][r]);
            }
}

// ---------------------------------------------------------------------------
extern "C" void kernel_launch(void* const* d_in, const int* in_sizes, int n_in,
                              void* d_out, int out_size, void* d_ws, size_t ws_size,
                              hipStream_t stream) {
    (void)in_sizes; (void)n_in; (void)out_size; (void)ws_size;
    const float* x    = (const float*)d_in[0];
    const float* cond = (const float*)d_in[1];
    const float* wq   = (const float*)d_in[2];
    const float* bq   = (const float*)d_in[3];
    const float* wkv  = (const float*)d_in[4];
    const float* bkv  = (const float*)d_in[5];
    const float* wp   = (const float*)d_in[6];
    const float* bp   = (const float*)d_in[7];

    const size_t MB = 1ull << 20;
    uint8_t* ws = (uint8_t*)d_ws;
    bf16_t* qxpk   = (bf16_t*)(ws + 0);        // 32MB qdq(x) packed; reused as o natural
    bf16_t* qpk    = (bf16_t*)(ws + 32 * MB);  // 32MB q packed; reused as qdq(o) packed
    bf16_t* wqpk   = (bf16_t*)(ws + 64 * MB);  // 8MB
    bf16_t* wkvpk  = (bf16_t*)(ws + 72 * MB);  // 16MB
    bf16_t* wppk   = (bf16_t*)(ws + 88 * MB);  // 8MB
    bf16_t* condpk = (bf16_t*)(ws + 96 * MB);  // 4MB
    bf16_t* kvpk   = (bf16_t*)(ws + 100 * MB); // 8MB (K 4MB | V 4MB)
    bf16_t* o_nat  = qxpk;
    bf16_t* opk    = qpk;

    dim3 blk(256);
    rowpack<1, float><<<8192, blk, 0, stream>>>(x, qxpk, 2048);
    rowpack<1, float><<<2048, blk, 0, stream>>>(wq, wqpk, 2048);
    rowpack<1, float><<<2048, blk, 0, stream>>>(wp, wppk, 2048);
    rowpack<0, float><<<1024, blk, 0, stream>>>(cond, condpk, 2048);
    rowpack<0, float><<<4096, blk, 0, stream>>>(wkv, wkvpk, 2048);
    // q = qdq(x) qdq(wq)^T + bq  -> attention-packed
    gemm_pk<0><<<dim3(16, 64), blk, 0, stream>>>(qxpk, wqpk, bq, qpk, 2048, 2048);
    // kv = cond wkv^T + bkv      -> packed K | packed V  (64-row tiles, 512 blocks)
    gemm_kv<<<dim3(32, 16), blk, 0, stream>>>(condpk, wkvpk, bkv, kvpk, 4096, 2048);
    // attention -> o natural
    attn64<<<dim3(64, 16, 2), blk, 0, stream>>>(qpk, kvpk, o_nat);
    // qdq(o) packed
    rowpack<1, bf16_t><<<8192, blk, 0, stream>>>(o_nat, opk, 2048);
    // out = qdq(o) qdq(wp)^T + bp -> natural fp32
    gemm_pk<1><<<dim3(16, 64), blk, 0, stream>>>(opk, wppk, bp, (float*)d_out, 2048, 2048);
}